// Round 1
// baseline (549.897 us; speedup 1.0000x reference)
//
#include <hip/hip_runtime.h>
#include <math.h>

#define Bb 128
#define Tt 1024
#define Ll 96

typedef float v2f __attribute__((ext_vector_type(2)));
typedef float v4f __attribute__((ext_vector_type(4)));

// One block per batch. 128 threads = 2 waves. Lane m (<96) owns state[m] and
// the E-column E[l][m] in registers. Per step: mat-vec in linear space over
// LDS-resident p[] (broadcast reads), then log/exp tail, ONE barrier.
__global__ __launch_bounds__(128, 1) void crf_fwd_kernel(
    const float* __restrict__ inputs,      // (B, T, L) fp32
    const int*   __restrict__ labels_idx,  // (B, T) int32
    const float* __restrict__ trans,       // (L, L) fp32
    float*       __restrict__ out)         // (B, 1) fp32
{
    const int b    = blockIdx.x;
    const int tid  = threadIdx.x;
    const int m    = tid;
    const int mm   = (m < Ll) ? m : (Ll - 1);   // clamp so lanes 96..127 stay valid
    const int wave = tid >> 6;

    __shared__ __align__(16) float pbuf[2][Ll]; // double-buffered p = exp(state - shift)
    __shared__ float vslot[2];                  // tval[0] per parity (stale-normalizer channel)
    __shared__ float wm[2];                     // wave partials (final reduction / scores)
    __shared__ float scoreslot[2];

    const float* xbase = inputs + (size_t)b * Tt * Ll;

    // ---- E[l] = exp(trans[l][m]) in 96 VGPRs (coalesced: lane m reads stride-1) ----
    float E[Ll];
    #pragma unroll
    for (int l = 0; l < Ll; ++l) {
        E[l] = __expf(trans[l * Ll + mm]);
    }

    // ---- point_score + trans_score (parallel over t across the block) ----
    {
        float psum = 0.f;
        const int* lbase = labels_idx + b * Tt;
        for (int t = tid; t < Tt; t += 128) {
            int i0 = lbase[t];
            psum += xbase[t * Ll + i0];
            if (t < Tt - 1) {
                int i1 = lbase[t + 1];
                psum += trans[i0 * Ll + i1];
            }
        }
        #pragma unroll
        for (int off = 32; off; off >>= 1) psum += __shfl_xor(psum, off, 64);
        if ((tid & 63) == 0) scoreslot[wave] = psum;
    }

    // ---- init: state_0 = inputs[b,0,:]; P_0 = exp(state_0 - 0) ----
    {
        float s0 = xbase[mm];
        if (m < Ll) pbuf[0][m] = __expf(s0);
    }
    __syncthreads();

    // ---- x prefetch pipeline, depth 3 ----
    float xa = xbase[1 * Ll + mm];
    float xb = xbase[2 * Ll + mm];
    float xc = xbase[3 * Ll + mm];

    // c: constant s.t. true state_t[m] = tval + c.  uP: shift used writing P_{t-1}.
    // uNext: shift to use writing P_t (stale: tval_{t-1}[0]).
    float c = 0.f, uP = 0.f, uNext = 0.f;
    float tval = 0.f;

    for (int t = 1; t < Tt; ++t) {
        const int w = t & 1, r = w ^ 1;

        // prefetch x row for step t+3
        float xn = 0.f;
        if (t + 3 < Tt) xn = xbase[(t + 3) * Ll + mm];

        // ---- acc = sum_l p[l] * E[l][m]  (broadcast b128 reads, packed fp32 FMA) ----
        v2f a0 = {0.f, 0.f}, a1 = {0.f, 0.f}, a2 = {0.f, 0.f}, a3 = {0.f, 0.f};
        #pragma unroll
        for (int j = 0; j < Ll / 4; ++j) {
            v4f p4 = *reinterpret_cast<const v4f*>(&pbuf[r][4 * j]);
            v2f plo = {p4.x, p4.y};
            v2f phi = {p4.z, p4.w};
            v2f elo = {E[4 * j], E[4 * j + 1]};
            v2f ehi = {E[4 * j + 2], E[4 * j + 3]};
            if (j & 1) { a2 += plo * elo; a3 += phi * ehi; }
            else       { a0 += plo * elo; a1 += phi * ehi; }
        }
        v2f as = (a0 + a1) + (a2 + a3);
        float total = as.x + as.y;

        c += uP;                          // c_t = c_{t-1} + shift(P_{t-1})
        tval = __logf(total) + xa;        // state_t[m] = tval + c
        float pn = __expf(tval - uNext);  // bounded: one-step increment + spread
        if (m < Ll)   pbuf[w][m] = pn;
        if (tid == 0) vslot[w]   = tval;
        uP = uNext;
        __syncthreads();
        uNext = vslot[w];                 // broadcast: tval_t[0], normalizer for next step

        xa = xb; xb = xc; xc = xn;
    }

    // ---- log_norm = logsumexp_m(tval + c) ----
    float cand = (m < Ll) ? tval : -INFINITY;
    #pragma unroll
    for (int off = 32; off; off >>= 1) cand = fmaxf(cand, __shfl_xor(cand, off, 64));
    if ((tid & 63) == 0) wm[wave] = cand;
    __syncthreads();
    float M = fmaxf(wm[0], wm[1]);

    float e = (m < Ll) ? __expf(tval - M) : 0.f;
    #pragma unroll
    for (int off = 32; off; off >>= 1) e += __shfl_xor(e, off, 64);
    if ((tid & 63) == 0) vslot[wave] = e;   // reuse as sum slots (main loop done)
    __syncthreads();

    if (tid == 0) {
        float lognorm = M + __logf(vslot[0] + vslot[1]) + c;
        float score   = scoreslot[0] + scoreslot[1];
        out[b] = lognorm - score;
    }
}

extern "C" void kernel_launch(void* const* d_in, const int* in_sizes, int n_in,
                              void* d_out, int out_size, void* d_ws, size_t ws_size,
                              hipStream_t stream) {
    const float* inputs     = (const float*)d_in[0];
    const int*   labels_idx = (const int*)d_in[1];
    const float* trans      = (const float*)d_in[2];
    float*       out        = (float*)d_out;

    crf_fwd_kernel<<<dim3(Bb), dim3(128), 0, stream>>>(inputs, labels_idx, trans, out);
}